// Round 1
// baseline (218.485 us; speedup 1.0000x reference)
//
#include <hip/hip_runtime.h>
#include <hip/hip_bf16.h>
#include <math.h>

// Problem constants (fixed by the reference):
#define N_  32
#define S_  4096
#define H_  16
#define E_  64
#define D_  64
#define CHUNK 512
#define NCHUNK (S_ / CHUNK)   // 8
#define NWAVE 4               // 256-thread block = 4 waves

// Kernel 1: per-(n,h,chunk) partial flash-attention.
// Each wave: lane = dim index (E=D=64). One s per iteration per wave,
// waves interleave s with stride NWAVE. Online softmax per wave, then
// LDS combine across the 4 waves -> one partial (m, l, acc[64]) per block.
__global__ __launch_bounds__(256, 8)
void attn_partial(const float* __restrict__ q,
                  const float* __restrict__ k,
                  const float* __restrict__ v,
                  const int* __restrict__ lens,
                  float* __restrict__ ws_m,
                  float* __restrict__ ws_l,
                  float* __restrict__ ws_acc)
{
    const int chunk = blockIdx.x;
    const int h     = blockIdx.y;
    const int n     = blockIdx.z;

    const int len = lens[n];
    const int s0  = chunk * CHUNK;
    if (s0 >= len) return;                       // dead chunk: no work, no writes
    const int s1  = min(s0 + CHUNK, len);

    const int lane = threadIdx.x & 63;
    const int wave = threadIdx.x >> 6;           // 0..3

    const float temp = 0.125f;                   // 1/sqrt(64)
    const float qv = q[(n * H_ + h) * E_ + lane];

    // bases for (n, *, h, lane)
    const float* kbase = k + ((size_t)n * S_ * H_ + h) * (size_t)E_ + lane;
    const float* vbase = v + ((size_t)n * S_ * H_ + h) * (size_t)D_ + lane;

    float m = -INFINITY, l = 0.f, acc = 0.f;

    for (int s = s0 + wave; s < s1; s += NWAVE) {
        float kx = kbase[(size_t)s * (H_ * E_)];
        float x  = qv * kx;
        // full-wave butterfly sum (64 lanes)
        #pragma unroll
        for (int off = 32; off > 0; off >>= 1)
            x += __shfl_xor(x, off, 64);
        float logit = temp * x;

        float mn = fmaxf(m, logit);
        float sc = __expf(m - mn);               // first iter: exp(-inf)=0
        float w  = __expf(logit - mn);
        float vx = vbase[(size_t)s * (H_ * D_)];
        l   = l * sc + w;
        acc = acc * sc + w * vx;
        m   = mn;
    }

    // combine the 4 waves
    __shared__ float sm[NWAVE], sl[NWAVE], sacc[NWAVE][64];
    if (lane == 0) { sm[wave] = m; sl[wave] = l; }
    sacc[wave][lane] = acc;
    __syncthreads();

    if (wave == 0) {
        float M = fmaxf(fmaxf(sm[0], sm[1]), fmaxf(sm[2], sm[3]));
        float L = 0.f, A = 0.f;
        #pragma unroll
        for (int wv = 0; wv < NWAVE; ++wv) {
            float e = __expf(sm[wv] - M);        // empty wave: exp(-inf - M) = 0
            L += sl[wv] * e;
            A += sacc[wv][lane] * e;
        }
        const size_t pidx = (size_t)(n * H_ + h) * NCHUNK + chunk;
        if (lane == 0) { ws_m[pidx] = M; ws_l[pidx] = L; }
        ws_acc[pidx * 64 + lane] = A;
    }
}

// Kernel 2: combine valid chunks per (n,h), normalize, write out [N,H,D].
__global__ __launch_bounds__(64, 8)
void attn_reduce(const int* __restrict__ lens,
                 const float* __restrict__ ws_m,
                 const float* __restrict__ ws_l,
                 const float* __restrict__ ws_acc,
                 float* __restrict__ out)
{
    const int nh = blockIdx.x;                   // 0 .. N*H-1
    const int n  = nh >> 4;                      // / H_
    const int h  = nh & (H_ - 1);
    const int lane = threadIdx.x;

    const int len = lens[n];
    const int nv  = (min(len, S_) + CHUNK - 1) / CHUNK;   // >= 1

    const size_t base = (size_t)(n * H_ + h) * NCHUNK;

    float M = -INFINITY;
    for (int c = 0; c < nv; ++c) M = fmaxf(M, ws_m[base + c]);

    float L = 0.f, A = 0.f;
    for (int c = 0; c < nv; ++c) {
        float e = __expf(ws_m[base + c] - M);
        L += ws_l[base + c] * e;
        A += ws_acc[(base + c) * 64 + lane] * e;
    }
    out[(size_t)nh * D_ + lane] = A / L;
}

extern "C" void kernel_launch(void* const* d_in, const int* in_sizes, int n_in,
                              void* d_out, int out_size, void* d_ws, size_t ws_size,
                              hipStream_t stream) {
    const float* q    = (const float*)d_in[0];   // [N,H,E]
    const float* k    = (const float*)d_in[1];   // [N,S,H,E]
    const float* v    = (const float*)d_in[2];   // [N,S,H,D]
    const int*   lens = (const int*)d_in[3];     // [N]
    float* out = (float*)d_out;                  // [N,H,D]

    // workspace layout: m[4096] | l[4096] | acc[4096*64]  (~1.03 MiB)
    float* ws_m   = (float*)d_ws;
    float* ws_l   = ws_m + (size_t)N_ * H_ * NCHUNK;
    float* ws_acc = ws_l + (size_t)N_ * H_ * NCHUNK;

    dim3 g1(NCHUNK, H_, N_);
    attn_partial<<<g1, 256, 0, stream>>>(q, k, v, lens, ws_m, ws_l, ws_acc);

    attn_reduce<<<N_ * H_, 64, 0, stream>>>(lens, ws_m, ws_l, ws_acc, out);
}

// Round 2
// 150.981 us; speedup vs baseline: 1.4471x; 1.4471x over previous
//
#include <hip/hip_runtime.h>
#include <hip/hip_bf16.h>
#include <math.h>

// Problem constants (fixed by the reference):
#define N_  32
#define S_  4096
#define H_  16
#define E_  64
#define D_  64
#define CHUNK 512
#define NCHUNK (S_ / CHUNK)   // 8
#define NWAVE 4               // 256-thread block = 4 waves

// Kernel 1: per-(n,h,chunk) partial flash-attention, float4-vectorized.
// Lane = (g, t): g = lane>>4 selects one of 4 s-positions per iteration,
// t = lane&15 covers dims 4t..4t+3. Each wave loads 4 K-vectors (1 KiB) and
// 4 V-vectors per iteration. Online softmax per 16-lane group; groups
// combine in-register, waves combine via LDS -> partial (m, l, acc[64]).
__global__ __launch_bounds__(256, 8)
void attn_partial(const float* __restrict__ q,
                  const float* __restrict__ k,
                  const float* __restrict__ v,
                  const int* __restrict__ lens,
                  float* __restrict__ ws_m,
                  float* __restrict__ ws_l,
                  float* __restrict__ ws_acc)
{
    const int chunk = blockIdx.x;
    const int h     = blockIdx.y;
    const int n     = blockIdx.z;

    const int len = lens[n];
    const int s0  = chunk * CHUNK;
    if (s0 >= len) return;                       // dead chunk: no work, no writes
    const int s1  = min(s0 + CHUNK, len);

    const int lane = threadIdx.x & 63;
    const int wave = threadIdx.x >> 6;           // 0..3
    const int t    = lane & 15;                  // dim quarter: e = 4t..4t+3
    const int g    = lane >> 4;                  // s sub-index within wave step

    const float temp = 0.125f;                   // 1/sqrt(64)
    const float4 q4 = *(const float4*)(q + (size_t)(n * H_ + h) * E_ + 4 * t);

    const float* kbase = k + ((size_t)n * S_ * H_ + h) * E_ + 4 * t;
    const float* vbase = v + ((size_t)n * S_ * H_ + h) * D_ + 4 * t;

    float  m = -1e30f, l = 0.f;
    float4 acc = make_float4(0.f, 0.f, 0.f, 0.f);

    for (int sb = s0 + wave * 4; sb < s1; sb += NWAVE * 4) {
        const int s     = sb + g;                // group-uniform
        const int s_eff = min(s, s1 - 1);        // clamp tail loads in-bounds
        const size_t off = (size_t)s_eff * (H_ * E_);
        const float4 k4 = *(const float4*)(kbase + off);
        const float4 v4 = *(const float4*)(vbase + off);

        float x = k4.x * q4.x + k4.y * q4.y + k4.z * q4.z + k4.w * q4.w;
        x += __shfl_xor(x, 1, 64);
        x += __shfl_xor(x, 2, 64);
        x += __shfl_xor(x, 4, 64);
        x += __shfl_xor(x, 8, 64);               // 16-lane group now has full dot
        const float logit = temp * x;

        const float mn = fmaxf(m, logit);
        const float sc = __expf(m - mn);
        float w = (s < s1) ? __expf(logit - mn) : 0.f;  // group-uniform predicate
        l     = l * sc + w;
        acc.x = acc.x * sc + w * v4.x;
        acc.y = acc.y * sc + w * v4.y;
        acc.z = acc.z * sc + w * v4.z;
        acc.w = acc.w * sc + w * v4.w;
        m = mn;
    }

    // combine the 4 groups within the wave (lanes t, t+16, t+32, t+48 share d)
    float M = m;
    M = fmaxf(M, __shfl_xor(M, 16, 64));
    M = fmaxf(M, __shfl_xor(M, 32, 64));
    const float e = __expf(m - M);               // empty group: exp(-1e30-M)=0
    l *= e;
    acc.x *= e; acc.y *= e; acc.z *= e; acc.w *= e;
    l     += __shfl_xor(l, 16, 64);     l     += __shfl_xor(l, 32, 64);
    acc.x += __shfl_xor(acc.x, 16, 64); acc.x += __shfl_xor(acc.x, 32, 64);
    acc.y += __shfl_xor(acc.y, 16, 64); acc.y += __shfl_xor(acc.y, 32, 64);
    acc.z += __shfl_xor(acc.z, 16, 64); acc.z += __shfl_xor(acc.z, 32, 64);
    acc.w += __shfl_xor(acc.w, 16, 64); acc.w += __shfl_xor(acc.w, 32, 64);

    // combine the 4 waves via LDS
    __shared__ float  sm[NWAVE], sl[NWAVE];
    __shared__ float4 sacc[NWAVE][16];
    if (lane == 0) { sm[wave] = M; sl[wave] = l; }
    if (lane < 16) sacc[wave][t] = acc;
    __syncthreads();

    if (wave == 0 && lane < 16) {
        const float Mb = fmaxf(fmaxf(sm[0], sm[1]), fmaxf(sm[2], sm[3]));
        float L = 0.f;
        float4 A = make_float4(0.f, 0.f, 0.f, 0.f);
        #pragma unroll
        for (int wv = 0; wv < NWAVE; ++wv) {
            const float ee = __expf(sm[wv] - Mb);   // empty wave contributes 0
            L += sl[wv] * ee;
            const float4 a = sacc[wv][t];
            A.x += a.x * ee; A.y += a.y * ee; A.z += a.z * ee; A.w += a.w * ee;
        }
        const size_t pidx = (size_t)(n * H_ + h) * NCHUNK + chunk;
        if (lane == 0) { ws_m[pidx] = Mb; ws_l[pidx] = L; }
        *(float4*)(ws_acc + pidx * 64 + 4 * t) = A;
    }
}

// Kernel 2: combine valid chunks per (n,h), normalize, write out [N,H,D].
__global__ __launch_bounds__(64, 8)
void attn_reduce(const int* __restrict__ lens,
                 const float* __restrict__ ws_m,
                 const float* __restrict__ ws_l,
                 const float* __restrict__ ws_acc,
                 float* __restrict__ out)
{
    const int nh = blockIdx.x;                   // 0 .. N*H-1
    const int n  = nh >> 4;                      // / H_
    const int h  = nh & (H_ - 1);
    const int lane = threadIdx.x;

    const int len = lens[n];
    const int nv  = (min(len, S_) + CHUNK - 1) / CHUNK;   // >= 1

    const size_t base = (size_t)(n * H_ + h) * NCHUNK;

    float M = -1e30f;
    for (int c = 0; c < nv; ++c) M = fmaxf(M, ws_m[base + c]);

    float L = 0.f, A = 0.f;
    for (int c = 0; c < nv; ++c) {
        const float e = __expf(ws_m[base + c] - M);
        L += ws_l[base + c] * e;
        A += ws_acc[(base + c) * 64 + lane] * e;
    }
    out[(size_t)nh * D_ + lane] = A / L;
}

extern "C" void kernel_launch(void* const* d_in, const int* in_sizes, int n_in,
                              void* d_out, int out_size, void* d_ws, size_t ws_size,
                              hipStream_t stream) {
    const float* q    = (const float*)d_in[0];   // [N,H,E]
    const float* k    = (const float*)d_in[1];   // [N,S,H,E]
    const float* v    = (const float*)d_in[2];   // [N,S,H,D]
    const int*   lens = (const int*)d_in[3];     // [N]
    float* out = (float*)d_out;                  // [N,H,D]

    // workspace layout: m[4096] | l[4096] | acc[4096*64]  (~1.03 MiB)
    float* ws_m   = (float*)d_ws;
    float* ws_l   = ws_m + (size_t)N_ * H_ * NCHUNK;
    float* ws_acc = ws_l + (size_t)N_ * H_ * NCHUNK;

    dim3 g1(NCHUNK, H_, N_);
    attn_partial<<<g1, 256, 0, stream>>>(q, k, v, lens, ws_m, ws_l, ws_acc);

    attn_reduce<<<N_ * H_, 64, 0, stream>>>(lens, ws_m, ws_l, ws_acc, out);
}

// Round 3
// 141.361 us; speedup vs baseline: 1.5456x; 1.0680x over previous
//
#include <hip/hip_runtime.h>
#include <hip/hip_bf16.h>
#include <math.h>

// Problem constants (fixed by the reference):
#define N_  32
#define S_  4096
#define H_  16
#define E_  64
#define D_  64
#define HE  (H_ * E_)   // 1024 floats = 4 KiB per s-row (same for V since D_==E_)

// Kernel 1: block = (chunk, n). 256 threads = 16 head-groups x 16 lanes.
// Per s the block reads the CONTIGUOUS 4 KiB row K[n,s,:,:] (one float4 per
// thread) and the matching V row; 16-lane group g computes head g's dot via
// 4 shfl_xor steps. Online softmax state (m,l) is replicated across the 16
// lanes of a group (identical updates), acc holds dims 4t..4t+3. Unroll x2
// over s amortizes the rescale. No divergence anywhere in the main loop.
__global__ __launch_bounds__(256, 8)
void attn_partial(const float* __restrict__ q,
                  const float* __restrict__ k,
                  const float* __restrict__ v,
                  const int* __restrict__ lens,
                  float* __restrict__ ws_m,
                  float* __restrict__ ws_l,
                  float* __restrict__ ws_acc,
                  int chunk_sz, int nchunk)
{
    const int chunk = blockIdx.x;
    const int n     = blockIdx.y;

    const int len = lens[n];
    const int s0  = chunk * chunk_sz;
    if (s0 >= len) return;                        // dead chunk: no work, no writes
    const int s1  = min(s0 + chunk_sz, len);

    const int tid = threadIdx.x;
    const int h   = tid >> 4;                     // head 0..15
    const int t   = tid & 15;                     // dim quarter: e = 4t..4t+3

    const float temp = 0.125f;                    // 1/sqrt(64)
    const float4 q4 = *(const float4*)(q + (size_t)(n * H_ + h) * E_ + 4 * t);

    const size_t elem = (size_t)h * E_ + 4 * t;
    const float* kp = k + (size_t)n * S_ * HE + (size_t)s0 * HE + elem;
    const float* vp = v + (size_t)n * S_ * HE + (size_t)s0 * HE + elem;

    float  m = -1e30f, l = 0.f;
    float4 acc = make_float4(0.f, 0.f, 0.f, 0.f);

    const int cnt   = s1 - s0;
    const int npair = cnt >> 1;

    for (int i = 0; i < npair; ++i) {
        const float4 ka = *(const float4*)(kp);
        const float4 kb = *(const float4*)(kp + HE);
        const float4 va = *(const float4*)(vp);
        const float4 vb = *(const float4*)(vp + HE);
        kp += 2 * HE; vp += 2 * HE;

        float xa = ka.x * q4.x + ka.y * q4.y + ka.z * q4.z + ka.w * q4.w;
        float xb = kb.x * q4.x + kb.y * q4.y + kb.z * q4.z + kb.w * q4.w;
        xa += __shfl_xor(xa, 1, 64);  xb += __shfl_xor(xb, 1, 64);
        xa += __shfl_xor(xa, 2, 64);  xb += __shfl_xor(xb, 2, 64);
        xa += __shfl_xor(xa, 4, 64);  xb += __shfl_xor(xb, 4, 64);
        xa += __shfl_xor(xa, 8, 64);  xb += __shfl_xor(xb, 8, 64);
        xa *= temp; xb *= temp;

        const float mn = fmaxf(m, fmaxf(xa, xb));
        const float sc = __expf(m - mn);
        const float wa = __expf(xa - mn);
        const float wb = __expf(xb - mn);
        l = l * sc + wa + wb;
        acc.x = acc.x * sc + wa * va.x + wb * vb.x;
        acc.y = acc.y * sc + wa * va.y + wb * vb.y;
        acc.z = acc.z * sc + wa * va.z + wb * vb.z;
        acc.w = acc.w * sc + wa * va.w + wb * vb.w;
        m = mn;
    }

    if (cnt & 1) {                                // block-uniform tail
        const float4 ka = *(const float4*)(kp);
        const float4 va = *(const float4*)(vp);
        float xa = ka.x * q4.x + ka.y * q4.y + ka.z * q4.z + ka.w * q4.w;
        xa += __shfl_xor(xa, 1, 64);
        xa += __shfl_xor(xa, 2, 64);
        xa += __shfl_xor(xa, 4, 64);
        xa += __shfl_xor(xa, 8, 64);
        xa *= temp;
        const float mn = fmaxf(m, xa);
        const float sc = __expf(m - mn);
        const float wa = __expf(xa - mn);
        l = l * sc + wa;
        acc.x = acc.x * sc + wa * va.x;
        acc.y = acc.y * sc + wa * va.y;
        acc.z = acc.z * sc + wa * va.z;
        acc.w = acc.w * sc + wa * va.w;
        m = mn;
    }

    // each group writes its head's partial directly (state replicated in-group)
    const size_t pidx = (size_t)(n * H_ + h) * nchunk + chunk;
    if (t == 0) { ws_m[pidx] = m; ws_l[pidx] = l; }
    *(float4*)(ws_acc + pidx * 64 + 4 * t) = acc;
}

// Kernel 2: combine valid chunks per (n,h), normalize, write out [N,H,D].
__global__ __launch_bounds__(64, 8)
void attn_reduce(const int* __restrict__ lens,
                 const float* __restrict__ ws_m,
                 const float* __restrict__ ws_l,
                 const float* __restrict__ ws_acc,
                 float* __restrict__ out,
                 int chunk_sz, int nchunk)
{
    const int nh = blockIdx.x;                    // n*H_ + h
    const int n  = nh >> 4;
    const int lane = threadIdx.x;

    const int len = lens[n];
    const int nv  = (min(len, S_) + chunk_sz - 1) / chunk_sz;   // >= 1

    const size_t base = (size_t)nh * nchunk;

    float M = -1e30f;
    for (int c = 0; c < nv; ++c) M = fmaxf(M, ws_m[base + c]);

    float L = 0.f, A = 0.f;
    for (int c = 0; c < nv; ++c) {
        const float e = __expf(ws_m[base + c] - M);
        L += ws_l[base + c] * e;
        A += ws_acc[(base + c) * 64 + lane] * e;
    }
    out[(size_t)nh * D_ + lane] = A / L;
}

extern "C" void kernel_launch(void* const* d_in, const int* in_sizes, int n_in,
                              void* d_out, int out_size, void* d_ws, size_t ws_size,
                              hipStream_t stream) {
    const float* q    = (const float*)d_in[0];   // [N,H,E]
    const float* k    = (const float*)d_in[1];   // [N,S,H,E]
    const float* v    = (const float*)d_in[2];   // [N,S,H,D]
    const int*   lens = (const int*)d_in[3];     // [N]
    float* out = (float*)d_out;                  // [N,H,D]

    const size_t NH = (size_t)N_ * H_;
    // pick the largest chunk count whose partials fit the workspace
    int nchunk = 8;
    if      (ws_size >= NH * 64 * 66 * sizeof(float)) nchunk = 64;  // ~8.7 MB
    else if (ws_size >= NH * 32 * 66 * sizeof(float)) nchunk = 32;
    else if (ws_size >= NH * 16 * 66 * sizeof(float)) nchunk = 16;
    const int chunk_sz = S_ / nchunk;

    float* ws_m   = (float*)d_ws;
    float* ws_l   = ws_m + NH * nchunk;
    float* ws_acc = ws_l + NH * nchunk;

    dim3 g1(nchunk, N_);
    attn_partial<<<g1, 256, 0, stream>>>(q, k, v, lens, ws_m, ws_l, ws_acc,
                                         chunk_sz, nchunk);

    attn_reduce<<<(int)NH, 64, 0, stream>>>(lens, ws_m, ws_l, ws_acc, out,
                                            chunk_sz, nchunk);
}

// Round 4
// 131.647 us; speedup vs baseline: 1.6596x; 1.0738x over previous
//
#include <hip/hip_runtime.h>
#include <hip/hip_bf16.h>
#include <math.h>

// Problem constants (fixed by the reference):
#define N_  32
#define S_  4096
#define H_  16
#define E_  64
#define D_  64
#define HE  (H_ * E_)   // 1024 floats = 4 KiB per s-row (same for V since D_==E_)

typedef float f32x4 __attribute__((ext_vector_type(4)));

// Kernel 1: block = (chunk, n). 256 threads = 16 head-groups x 16 lanes.
// Per s the block reads the CONTIGUOUS 4 KiB row K[n,s,:,:] (one float4 per
// thread, non-temporal) and the matching V row; 16-lane group h computes head
// h's dot via 4 shfl_xor steps. Online softmax state (m,l) is replicated
// across the 16 lanes of a group; acc holds dims 4t..4t+3. Unroll x2 over s.
__global__ __launch_bounds__(256, 8)
void attn_partial(const float* __restrict__ q,
                  const float* __restrict__ k,
                  const float* __restrict__ v,
                  const int* __restrict__ lens,
                  float* __restrict__ ws_m,
                  float* __restrict__ ws_l,
                  float* __restrict__ ws_acc,
                  int chunk_sz, int nchunk)
{
    const int chunk = blockIdx.x;
    const int n     = blockIdx.y;

    const int len = lens[n];
    const int s0  = chunk * chunk_sz;
    if (s0 >= len) return;                        // dead chunk: no work, no writes
    const int s1  = min(s0 + chunk_sz, len);

    const int tid = threadIdx.x;
    const int h   = tid >> 4;                     // head 0..15
    const int t   = tid & 15;                     // dim quarter: e = 4t..4t+3

    const float temp = 0.125f;                    // 1/sqrt(64)
    const f32x4 q4 = *(const f32x4*)(q + (size_t)(n * H_ + h) * E_ + 4 * t);

    const size_t elem = (size_t)h * E_ + 4 * t;
    const float* kp = k + (size_t)n * S_ * HE + (size_t)s0 * HE + elem;
    const float* vp = v + (size_t)n * S_ * HE + (size_t)s0 * HE + elem;

    float m = -1e30f, l = 0.f;
    f32x4 acc = (f32x4)0.f;

    const int cnt   = s1 - s0;
    const int npair = cnt >> 1;

    for (int i = 0; i < npair; ++i) {
        const f32x4 ka = __builtin_nontemporal_load((const f32x4*)kp);
        const f32x4 kb = __builtin_nontemporal_load((const f32x4*)(kp + HE));
        const f32x4 va = __builtin_nontemporal_load((const f32x4*)vp);
        const f32x4 vb = __builtin_nontemporal_load((const f32x4*)(vp + HE));
        kp += 2 * HE; vp += 2 * HE;

        float xa = ka.x * q4.x + ka.y * q4.y + ka.z * q4.z + ka.w * q4.w;
        float xb = kb.x * q4.x + kb.y * q4.y + kb.z * q4.z + kb.w * q4.w;
        xa += __shfl_xor(xa, 1, 64);  xb += __shfl_xor(xb, 1, 64);
        xa += __shfl_xor(xa, 2, 64);  xb += __shfl_xor(xb, 2, 64);
        xa += __shfl_xor(xa, 4, 64);  xb += __shfl_xor(xb, 4, 64);
        xa += __shfl_xor(xa, 8, 64);  xb += __shfl_xor(xb, 8, 64);
        xa *= temp; xb *= temp;

        const float mn = fmaxf(m, fmaxf(xa, xb));
        const float sc = __expf(m - mn);
        const float wa = __expf(xa - mn);
        const float wb = __expf(xb - mn);
        l = l * sc + wa + wb;
        acc.x = acc.x * sc + wa * va.x + wb * vb.x;
        acc.y = acc.y * sc + wa * va.y + wb * vb.y;
        acc.z = acc.z * sc + wa * va.z + wb * vb.z;
        acc.w = acc.w * sc + wa * va.w + wb * vb.w;
        m = mn;
    }

    if (cnt & 1) {                                // block-uniform tail
        const f32x4 ka = __builtin_nontemporal_load((const f32x4*)kp);
        const f32x4 va = __builtin_nontemporal_load((const f32x4*)vp);
        float xa = ka.x * q4.x + ka.y * q4.y + ka.z * q4.z + ka.w * q4.w;
        xa += __shfl_xor(xa, 1, 64);
        xa += __shfl_xor(xa, 2, 64);
        xa += __shfl_xor(xa, 4, 64);
        xa += __shfl_xor(xa, 8, 64);
        xa *= temp;
        const float mn = fmaxf(m, xa);
        const float sc = __expf(m - mn);
        const float wa = __expf(xa - mn);
        l = l * sc + wa;
        acc.x = acc.x * sc + wa * va.x;
        acc.y = acc.y * sc + wa * va.y;
        acc.z = acc.z * sc + wa * va.z;
        acc.w = acc.w * sc + wa * va.w;
        m = mn;
    }

    // each group writes its head's partial directly (state replicated in-group)
    const size_t pidx = (size_t)(n * H_ + h) * nchunk + chunk;
    if (t == 0) { ws_m[pidx] = m; ws_l[pidx] = l; }
    *(f32x4*)(ws_acc + pidx * 64 + 4 * t) = acc;
}

// Kernel 2: combine valid chunks per (n,h), normalize, write out [N,H,D].
__global__ __launch_bounds__(64, 8)
void attn_reduce(const int* __restrict__ lens,
                 const float* __restrict__ ws_m,
                 const float* __restrict__ ws_l,
                 const float* __restrict__ ws_acc,
                 float* __restrict__ out,
                 int chunk_sz, int nchunk)
{
    const int nh = blockIdx.x;                    // n*H_ + h
    const int n  = nh >> 4;
    const int lane = threadIdx.x;

    const int len = lens[n];
    const int nv  = (min(len, S_) + chunk_sz - 1) / chunk_sz;   // >= 1

    const size_t base = (size_t)nh * nchunk;

    float M = -1e30f;
    for (int c = 0; c < nv; ++c) M = fmaxf(M, ws_m[base + c]);

    float L = 0.f, A = 0.f;
    for (int c = 0; c < nv; ++c) {
        const float e = __expf(ws_m[base + c] - M);
        L += ws_l[base + c] * e;
        A += ws_acc[(base + c) * 64 + lane] * e;
    }
    out[(size_t)nh * D_ + lane] = A / L;
}

extern "C" void kernel_launch(void* const* d_in, const int* in_sizes, int n_in,
                              void* d_out, int out_size, void* d_ws, size_t ws_size,
                              hipStream_t stream) {
    const float* q    = (const float*)d_in[0];   // [N,H,E]
    const float* k    = (const float*)d_in[1];   // [N,S,H,E]
    const float* v    = (const float*)d_in[2];   // [N,S,H,D]
    const int*   lens = (const int*)d_in[3];     // [N]
    float* out = (float*)d_out;                  // [N,H,D]

    const size_t NH = (size_t)N_ * H_;
    // pick the largest chunk count whose partials fit the workspace
    int nchunk = 8;
    if      (ws_size >= NH * 128 * 66 * sizeof(float)) nchunk = 128; // ~17.3 MB
    else if (ws_size >= NH * 64  * 66 * sizeof(float)) nchunk = 64;
    else if (ws_size >= NH * 32  * 66 * sizeof(float)) nchunk = 32;
    else if (ws_size >= NH * 16  * 66 * sizeof(float)) nchunk = 16;
    const int chunk_sz = S_ / nchunk;

    float* ws_m   = (float*)d_ws;
    float* ws_l   = ws_m + NH * nchunk;
    float* ws_acc = ws_l + NH * nchunk;

    dim3 g1(nchunk, N_);
    attn_partial<<<g1, 256, 0, stream>>>(q, k, v, lens, ws_m, ws_l, ws_acc,
                                         chunk_sz, nchunk);

    attn_reduce<<<(int)NH, 64, 0, stream>>>(lens, ws_m, ws_l, ws_acc, out,
                                            chunk_sz, nchunk);
}

// Round 5
// 130.631 us; speedup vs baseline: 1.6725x; 1.0078x over previous
//
#include <hip/hip_runtime.h>
#include <hip/hip_bf16.h>
#include <math.h>

// Problem constants (fixed by the reference):
#define N_  32
#define S_  4096
#define H_  16
#define E_  64
#define D_  64
#define HE  (H_ * E_)   // 1024 floats = 4 KiB per s-row (same for V since D_==E_)

typedef float f32x4 __attribute__((ext_vector_type(4)));

// Kernel 1: block = (chunk, n). 256 threads = 16 head-groups x 16 lanes.
// Per s the block reads the CONTIGUOUS 4 KiB row K[n,s,:,:] and V row
// (one float4/thread, non-temporal). Software-pipelined: iteration i+1's
// loads are issued before iteration i's registers are consumed, so the
// compiler waits at vmcnt(4) instead of vmcnt(0) and each wave keeps a
// 4 KB load batch in flight during its compute.
__global__ __launch_bounds__(256, 6)
void attn_partial(const float* __restrict__ q,
                  const float* __restrict__ k,
                  const float* __restrict__ v,
                  const int* __restrict__ lens,
                  float* __restrict__ ws_m,
                  float* __restrict__ ws_l,
                  float* __restrict__ ws_acc,
                  int chunk_sz, int nchunk)
{
    const int chunk = blockIdx.x;
    const int n     = blockIdx.y;

    const int len = lens[n];
    const int s0  = chunk * chunk_sz;
    if (s0 >= len) return;                        // dead chunk: no work, no writes
    const int s1  = min(s0 + chunk_sz, len);

    const int tid = threadIdx.x;
    const int h   = tid >> 4;                     // head 0..15
    const int t   = tid & 15;                     // dim quarter: e = 4t..4t+3

    f32x4 q4 = *(const f32x4*)(q + (size_t)(n * H_ + h) * E_ + 4 * t);
    q4 *= 0.125f;                                 // fold 1/sqrt(64) into q

    const size_t elem = (size_t)h * E_ + 4 * t;
    const float* kp = k + (size_t)n * S_ * HE + (size_t)s0 * HE + elem;
    const float* vp = v + (size_t)n * S_ * HE + (size_t)s0 * HE + elem;

    float m = -1e30f, l = 0.f;
    f32x4 acc = (f32x4)0.f;

    const int cnt   = s1 - s0;
    const int npair = cnt >> 1;

    // one softmax/accumulate step over two s-rows held in registers
    auto consume = [&](const f32x4& Ka, const f32x4& Kb,
                       const f32x4& Va, const f32x4& Vb) {
        float xa = Ka.x * q4.x + Ka.y * q4.y + Ka.z * q4.z + Ka.w * q4.w;
        float xb = Kb.x * q4.x + Kb.y * q4.y + Kb.z * q4.z + Kb.w * q4.w;
        xa += __shfl_xor(xa, 1, 64);  xb += __shfl_xor(xb, 1, 64);
        xa += __shfl_xor(xa, 2, 64);  xb += __shfl_xor(xb, 2, 64);
        xa += __shfl_xor(xa, 4, 64);  xb += __shfl_xor(xb, 4, 64);
        xa += __shfl_xor(xa, 8, 64);  xb += __shfl_xor(xb, 8, 64);

        const float mn = fmaxf(m, fmaxf(xa, xb));
        const float sc = __expf(m - mn);
        const float wa = __expf(xa - mn);
        const float wb = __expf(xb - mn);
        l = l * sc + wa + wb;
        acc.x = acc.x * sc + wa * Va.x + wb * Vb.x;
        acc.y = acc.y * sc + wa * Va.y + wb * Vb.y;
        acc.z = acc.z * sc + wa * Va.z + wb * Vb.z;
        acc.w = acc.w * sc + wa * Va.w + wb * Vb.w;
        m = mn;
    };

    if (npair > 0) {
        // prologue: load pair 0
        f32x4 ka = __builtin_nontemporal_load((const f32x4*)kp);
        f32x4 kb = __builtin_nontemporal_load((const f32x4*)(kp + HE));
        f32x4 va = __builtin_nontemporal_load((const f32x4*)vp);
        f32x4 vb = __builtin_nontemporal_load((const f32x4*)(vp + HE));
        kp += 2 * HE; vp += 2 * HE;

        for (int i = 1; i < npair; ++i) {
            // issue next pair's loads BEFORE consuming the current pair
            const f32x4 ka2 = __builtin_nontemporal_load((const f32x4*)kp);
            const f32x4 kb2 = __builtin_nontemporal_load((const f32x4*)(kp + HE));
            const f32x4 va2 = __builtin_nontemporal_load((const f32x4*)vp);
            const f32x4 vb2 = __builtin_nontemporal_load((const f32x4*)(vp + HE));
            kp += 2 * HE; vp += 2 * HE;

            consume(ka, kb, va, vb);

            ka = ka2; kb = kb2; va = va2; vb = vb2;
        }
        consume(ka, kb, va, vb);                  // epilogue pair
    }

    if (cnt & 1) {                                // block-uniform odd tail row
        const f32x4 ka = __builtin_nontemporal_load((const f32x4*)kp);
        const f32x4 va = __builtin_nontemporal_load((const f32x4*)vp);
        float xa = ka.x * q4.x + ka.y * q4.y + ka.z * q4.z + ka.w * q4.w;
        xa += __shfl_xor(xa, 1, 64);
        xa += __shfl_xor(xa, 2, 64);
        xa += __shfl_xor(xa, 4, 64);
        xa += __shfl_xor(xa, 8, 64);
        const float mn = fmaxf(m, xa);
        const float sc = __expf(m - mn);
        const float wa = __expf(xa - mn);
        l = l * sc + wa;
        acc.x = acc.x * sc + wa * va.x;
        acc.y = acc.y * sc + wa * va.y;
        acc.z = acc.z * sc + wa * va.z;
        acc.w = acc.w * sc + wa * va.w;
        m = mn;
    }

    // each group writes its head's partial directly (state replicated in-group)
    const size_t pidx = (size_t)(n * H_ + h) * nchunk + chunk;
    if (t == 0) { ws_m[pidx] = m; ws_l[pidx] = l; }
    *(f32x4*)(ws_acc + pidx * 64 + 4 * t) = acc;
}

// Kernel 2: combine valid chunks per (n,h), normalize, write out [N,H,D].
__global__ __launch_bounds__(64, 8)
void attn_reduce(const int* __restrict__ lens,
                 const float* __restrict__ ws_m,
                 const float* __restrict__ ws_l,
                 const float* __restrict__ ws_acc,
                 float* __restrict__ out,
                 int chunk_sz, int nchunk)
{
    const int nh = blockIdx.x;                    // n*H_ + h
    const int n  = nh >> 4;
    const int lane = threadIdx.x;

    const int len = lens[n];
    const int nv  = (min(len, S_) + chunk_sz - 1) / chunk_sz;   // >= 1

    const size_t base = (size_t)nh * nchunk;

    float M = -1e30f;
    for (int c = 0; c < nv; ++c) M = fmaxf(M, ws_m[base + c]);

    float L = 0.f, A = 0.f;
    for (int c = 0; c < nv; ++c) {
        const float e = __expf(ws_m[base + c] - M);
        L += ws_l[base + c] * e;
        A += ws_acc[(base + c) * 64 + lane] * e;
    }
    out[(size_t)nh * D_ + lane] = A / L;
}

extern "C" void kernel_launch(void* const* d_in, const int* in_sizes, int n_in,
                              void* d_out, int out_size, void* d_ws, size_t ws_size,
                              hipStream_t stream) {
    const float* q    = (const float*)d_in[0];   // [N,H,E]
    const float* k    = (const float*)d_in[1];   // [N,S,H,E]
    const float* v    = (const float*)d_in[2];   // [N,S,H,D]
    const int*   lens = (const int*)d_in[3];     // [N]
    float* out = (float*)d_out;                  // [N,H,D]

    const size_t NH = (size_t)N_ * H_;
    // pick the largest chunk count whose partials fit the workspace
    int nchunk = 8;
    if      (ws_size >= NH * 128 * 66 * sizeof(float)) nchunk = 128; // ~17.3 MB
    else if (ws_size >= NH * 64  * 66 * sizeof(float)) nchunk = 64;
    else if (ws_size >= NH * 32  * 66 * sizeof(float)) nchunk = 32;
    else if (ws_size >= NH * 16  * 66 * sizeof(float)) nchunk = 16;
    const int chunk_sz = S_ / nchunk;

    float* ws_m   = (float*)d_ws;
    float* ws_l   = ws_m + NH * nchunk;
    float* ws_acc = ws_l + NH * nchunk;

    dim3 g1(nchunk, N_);
    attn_partial<<<g1, 256, 0, stream>>>(q, k, v, lens, ws_m, ws_l, ws_acc,
                                         chunk_sz, nchunk);

    attn_reduce<<<(int)NH, 64, 0, stream>>>(lens, ws_m, ws_l, ws_acc, out,
                                            chunk_sz, nchunk);
}

// Round 6
// 98.476 us; speedup vs baseline: 2.2187x; 1.3265x over previous
//
#include <hip/hip_runtime.h>
#include <hip/hip_bf16.h>
#include <math.h>

// Problem constants (fixed by the reference):
#define N_  32
#define S_  4096
#define H_  16
#define E_  64
#define D_  64
#define HE  (H_ * E_)   // 1024 floats = 4 KiB per s-row (same for V since D_==E_)

typedef float f32x4 __attribute__((ext_vector_type(4)));

// Kernel 1: block = (chunk, n). 256 threads = 16 head-groups x 16 lanes.
// Per s the block reads the CONTIGUOUS 4 KiB row K[n,s,:,:] and V row
// (one float4/thread, non-temporal). Software-pipelined one pair ahead.
__global__ __launch_bounds__(256, 6)
void attn_partial(const float* __restrict__ q,
                  const float* __restrict__ k,
                  const float* __restrict__ v,
                  const int* __restrict__ lens,
                  float* __restrict__ ws_m,
                  float* __restrict__ ws_l,
                  float* __restrict__ ws_acc,
                  int chunk_sz, int nchunk)
{
    const int chunk = blockIdx.x;
    const int n     = blockIdx.y;

    const int len = lens[n];
    const int s0  = chunk * chunk_sz;
    if (s0 >= len) return;                        // dead chunk: no work, no writes
    const int s1  = min(s0 + chunk_sz, len);

    const int tid = threadIdx.x;
    const int h   = tid >> 4;                     // head 0..15
    const int t   = tid & 15;                     // dim quarter: e = 4t..4t+3

    f32x4 q4 = *(const f32x4*)(q + (size_t)(n * H_ + h) * E_ + 4 * t);
    q4 *= 0.125f;                                 // fold 1/sqrt(64) into q

    const size_t elem = (size_t)h * E_ + 4 * t;
    const float* kp = k + (size_t)n * S_ * HE + (size_t)s0 * HE + elem;
    const float* vp = v + (size_t)n * S_ * HE + (size_t)s0 * HE + elem;

    float m = -1e30f, l = 0.f;
    f32x4 acc = (f32x4)0.f;

    const int cnt   = s1 - s0;
    const int npair = cnt >> 1;

    auto consume = [&](const f32x4& Ka, const f32x4& Kb,
                       const f32x4& Va, const f32x4& Vb) {
        float xa = Ka.x * q4.x + Ka.y * q4.y + Ka.z * q4.z + Ka.w * q4.w;
        float xb = Kb.x * q4.x + Kb.y * q4.y + Kb.z * q4.z + Kb.w * q4.w;
        xa += __shfl_xor(xa, 1, 64);  xb += __shfl_xor(xb, 1, 64);
        xa += __shfl_xor(xa, 2, 64);  xb += __shfl_xor(xb, 2, 64);
        xa += __shfl_xor(xa, 4, 64);  xb += __shfl_xor(xb, 4, 64);
        xa += __shfl_xor(xa, 8, 64);  xb += __shfl_xor(xb, 8, 64);

        const float mn = fmaxf(m, fmaxf(xa, xb));
        const float sc = __expf(m - mn);
        const float wa = __expf(xa - mn);
        const float wb = __expf(xb - mn);
        l = l * sc + wa + wb;
        acc.x = acc.x * sc + wa * Va.x + wb * Vb.x;
        acc.y = acc.y * sc + wa * Va.y + wb * Vb.y;
        acc.z = acc.z * sc + wa * Va.z + wb * Vb.z;
        acc.w = acc.w * sc + wa * Va.w + wb * Vb.w;
        m = mn;
    };

    if (npair > 0) {
        f32x4 ka = __builtin_nontemporal_load((const f32x4*)kp);
        f32x4 kb = __builtin_nontemporal_load((const f32x4*)(kp + HE));
        f32x4 va = __builtin_nontemporal_load((const f32x4*)vp);
        f32x4 vb = __builtin_nontemporal_load((const f32x4*)(vp + HE));
        kp += 2 * HE; vp += 2 * HE;

        for (int i = 1; i < npair; ++i) {
            const f32x4 ka2 = __builtin_nontemporal_load((const f32x4*)kp);
            const f32x4 kb2 = __builtin_nontemporal_load((const f32x4*)(kp + HE));
            const f32x4 va2 = __builtin_nontemporal_load((const f32x4*)vp);
            const f32x4 vb2 = __builtin_nontemporal_load((const f32x4*)(vp + HE));
            kp += 2 * HE; vp += 2 * HE;

            consume(ka, kb, va, vb);

            ka = ka2; kb = kb2; va = va2; vb = vb2;
        }
        consume(ka, kb, va, vb);
    }

    if (cnt & 1) {                                // block-uniform odd tail row
        const f32x4 ka = __builtin_nontemporal_load((const f32x4*)kp);
        const f32x4 va = __builtin_nontemporal_load((const f32x4*)vp);
        float xa = ka.x * q4.x + ka.y * q4.y + ka.z * q4.z + ka.w * q4.w;
        xa += __shfl_xor(xa, 1, 64);
        xa += __shfl_xor(xa, 2, 64);
        xa += __shfl_xor(xa, 4, 64);
        xa += __shfl_xor(xa, 8, 64);
        const float mn = fmaxf(m, xa);
        const float sc = __expf(m - mn);
        const float wa = __expf(xa - mn);
        l = l * sc + wa;
        acc.x = acc.x * sc + wa * va.x;
        acc.y = acc.y * sc + wa * va.y;
        acc.z = acc.z * sc + wa * va.z;
        acc.w = acc.w * sc + wa * va.w;
        m = mn;
    }

    const size_t pidx = (size_t)(n * H_ + h) * nchunk + chunk;
    if (t == 0) { ws_m[pidx] = m; ws_l[pidx] = l; }
    *(f32x4*)(ws_acc + pidx * 64 + 4 * t) = acc;
}

// Kernel 2: block = (n,h), 256 threads = 16 (wave,g) groups x 16 lanes.
// Each (wave,g) group online-merges chunks c = wave*4+g, +16, +32, ... in a
// single pass (f32x4 partial reads). Groups combine via shfl(16,32), waves
// via LDS. Max serial dependent-load depth: ceil(nv/16) <= 8.
__global__ __launch_bounds__(256, 8)
void attn_reduce(const int* __restrict__ lens,
                 const float* __restrict__ ws_m,
                 const float* __restrict__ ws_l,
                 const float* __restrict__ ws_acc,
                 float* __restrict__ out,
                 int chunk_sz, int nchunk)
{
    const int nh = blockIdx.x;                    // n*H_ + h
    const int n  = nh >> 4;
    const int tid  = threadIdx.x;
    const int wave = tid >> 6;                    // 0..3
    const int lane = tid & 63;
    const int g    = lane >> 4;                   // chunk sub-index 0..3
    const int t    = lane & 15;                   // dim quarter: d = 4t..4t+3

    const int len = lens[n];
    const int nv  = (min(len, S_) + chunk_sz - 1) / chunk_sz;   // >= 1

    const size_t base = (size_t)nh * nchunk;

    float m = -1e30f, l = 0.f;
    f32x4 acc = (f32x4)0.f;

    #pragma unroll 2
    for (int c = wave * 4 + g; c < nv; c += 16) {
        const float mc = ws_m[base + c];          // broadcast within group
        const float lc = ws_l[base + c];
        const f32x4 ac = *(const f32x4*)(ws_acc + (base + c) * 64 + 4 * t);
        const float mn = fmaxf(m, mc);
        const float so = __expf(m - mn);
        const float sn = __expf(mc - mn);
        l = l * so + lc * sn;
        acc.x = acc.x * so + ac.x * sn;
        acc.y = acc.y * so + ac.y * sn;
        acc.z = acc.z * so + ac.z * sn;
        acc.w = acc.w * so + ac.w * sn;
        m = mn;
    }

    // combine the 4 g-groups within the wave
    float M = m;
    M = fmaxf(M, __shfl_xor(M, 16, 64));
    M = fmaxf(M, __shfl_xor(M, 32, 64));
    const float e = __expf(m - M);                // empty group: l=0, acc=0 anyway
    l *= e;
    acc.x *= e; acc.y *= e; acc.z *= e; acc.w *= e;
    l     += __shfl_xor(l, 16, 64);     l     += __shfl_xor(l, 32, 64);
    acc.x += __shfl_xor(acc.x, 16, 64); acc.x += __shfl_xor(acc.x, 32, 64);
    acc.y += __shfl_xor(acc.y, 16, 64); acc.y += __shfl_xor(acc.y, 32, 64);
    acc.z += __shfl_xor(acc.z, 16, 64); acc.z += __shfl_xor(acc.z, 32, 64);
    acc.w += __shfl_xor(acc.w, 16, 64); acc.w += __shfl_xor(acc.w, 32, 64);

    // combine the 4 waves via LDS
    __shared__ float sm[4], sl[4];
    __shared__ f32x4 sacc[4][16];
    if (lane == 0) { sm[wave] = M; sl[wave] = l; }
    if (lane < 16) sacc[wave][t] = acc;
    __syncthreads();

    if (wave == 0 && lane < 16) {
        const float Mb = fmaxf(fmaxf(sm[0], sm[1]), fmaxf(sm[2], sm[3]));
        float L = 0.f;
        f32x4 A = (f32x4)0.f;
        #pragma unroll
        for (int wv = 0; wv < 4; ++wv) {
            const float ee = __expf(sm[wv] - Mb); // empty wave contributes 0
            L += sl[wv] * ee;
            const f32x4 a = sacc[wv][t];
            A.x += a.x * ee; A.y += a.y * ee; A.z += a.z * ee; A.w += a.w * ee;
        }
        const float inv = 1.f / L;
        f32x4 O; O.x = A.x * inv; O.y = A.y * inv; O.z = A.z * inv; O.w = A.w * inv;
        *(f32x4*)(out + (size_t)nh * D_ + 4 * t) = O;
    }
}

extern "C" void kernel_launch(void* const* d_in, const int* in_sizes, int n_in,
                              void* d_out, int out_size, void* d_ws, size_t ws_size,
                              hipStream_t stream) {
    const float* q    = (const float*)d_in[0];   // [N,H,E]
    const float* k    = (const float*)d_in[1];   // [N,S,H,E]
    const float* v    = (const float*)d_in[2];   // [N,S,H,D]
    const int*   lens = (const int*)d_in[3];     // [N]
    float* out = (float*)d_out;                  // [N,H,D]

    const size_t NH = (size_t)N_ * H_;
    // pick the largest chunk count whose partials fit the workspace
    int nchunk = 8;
    if      (ws_size >= NH * 128 * 66 * sizeof(float)) nchunk = 128; // ~17.3 MB
    else if (ws_size >= NH * 64  * 66 * sizeof(float)) nchunk = 64;
    else if (ws_size >= NH * 32  * 66 * sizeof(float)) nchunk = 32;
    else if (ws_size >= NH * 16  * 66 * sizeof(float)) nchunk = 16;
    const int chunk_sz = S_ / nchunk;

    float* ws_m   = (float*)d_ws;
    float* ws_l   = ws_m + NH * nchunk;
    float* ws_acc = ws_l + NH * nchunk;

    dim3 g1(nchunk, N_);
    attn_partial<<<g1, 256, 0, stream>>>(q, k, v, lens, ws_m, ws_l, ws_acc,
                                         chunk_sz, nchunk);

    attn_reduce<<<(int)NH, 256, 0, stream>>>(lens, ws_m, ws_l, ws_acc, out,
                                             chunk_sz, nchunk);
}